// Round 2
// baseline (342.467 us; speedup 1.0000x reference)
//
#include <hip/hip_runtime.h>
#include <hip/hip_bf16.h>
#include <stdint.h>

#define NTOK 4096
#define DIM  256
#define NH   8
#define HD   32

typedef __attribute__((ext_vector_type(8))) short short8;
typedef __attribute__((ext_vector_type(4))) float float4v;
typedef unsigned short u16;
typedef unsigned int u32;

__device__ __forceinline__ float bf2f(u16 u) {
    union { u32 u; float f; } c; c.u = ((u32)u) << 16; return c.f;
}
__device__ __forceinline__ u16 f2bf(float f) {
    union { float f; u32 u; } c; c.f = f;
    u32 u = c.u;
    u = u + 0x7FFFu + ((u >> 16) & 1u);   // round-to-nearest-even
    return (u16)(u >> 16);
}

// ---------------- kernel A: x (f32) -> bf16 ----------------
__global__ void x_to_bf16(const float* __restrict__ x, u16* __restrict__ xb) {
    int i = (blockIdx.x * blockDim.x + threadIdx.x) * 4;   // 1048576 elements
    float4 v = *(const float4*)(x + i);
    ushort4 o;
    o.x = f2bf(v.x); o.y = f2bf(v.y); o.z = f2bf(v.z); o.w = f2bf(v.w);
    *(ushort4*)(xb + i) = o;
}

// ---------------- kernel 0: transpose weights (f32 256x256 -> bf16 WT) ----------------
__global__ void transpose_w(const float* __restrict__ Wq, const float* __restrict__ Wk,
                            const float* __restrict__ Wv, const float* __restrict__ Wo,
                            u16* __restrict__ WT) {
    const float* srcs[4] = {Wq, Wk, Wv, Wo};
    const float* W = srcs[blockIdx.y];
    int o = blockIdx.x, i = threadIdx.x;
    WT[blockIdx.y * 65536 + o * 256 + i] = f2bf(W[i * 256 + o]);
}

// ---------------- kernel 1: adj (f32 0/1) -> bitmask ----------------
// block of 256 threads handles 1024 elements -> 32 output words
__global__ __launch_bounds__(256) void adj_to_bits(const float* __restrict__ adj,
                                                   u32* __restrict__ bits) {
    __shared__ u32 nib[256];
    int t = threadIdx.x;
    size_t base = (size_t)blockIdx.x * 1024 + t * 4;
    const uint4 v = *(const uint4*)(adj + base);   // 4 f32, nonzero test on bits
    u32 n = 0;
    if (v.x) n |= 1u;
    if (v.y) n |= 2u;
    if (v.z) n |= 4u;
    if (v.w) n |= 8u;
    nib[t] = n << ((t & 7) * 4);
    __syncthreads();
    if (t < 32) {
        u32 w = 0;
#pragma unroll
        for (int i = 0; i < 8; ++i) w |= nib[t * 8 + i];
        bits[(size_t)blockIdx.x * 32 + t] = w;
    }
}

// ---------------- kernel 2: QKV projection ----------------
// grid (mtile=256, ntile=16, mat=3), block 64 (one wave per 16x16 tile)
// mat 0 -> Q[m][n], mat 1 -> K[m][n], mat 2 -> VT[n][m]  (V transposed)
__global__ __launch_bounds__(64) void qkv_gemm(
    const u16* __restrict__ xb,
    const u16* __restrict__ WT,   // 3 transposed weights at mat*65536 (Wq,Wk,Wv)
    const float* __restrict__ bq, const float* __restrict__ bk, const float* __restrict__ bv,
    u16* __restrict__ Q, u16* __restrict__ K, u16* __restrict__ VT) {
    int lane = threadIdx.x, quad = lane >> 4, l16 = lane & 15;
    int mtile = blockIdx.x, ntile = blockIdx.y, mat = blockIdx.z;
    const float* bias = (mat == 0) ? bq : (mat == 1) ? bk : bv;
    const u16* arow = xb + (size_t)(mtile * 16 + l16) * DIM + quad * 8;
    const u16* brow = WT + (size_t)mat * 65536 + (size_t)(ntile * 16 + l16) * DIM + quad * 8;
    float4v acc = {0.f, 0.f, 0.f, 0.f};
#pragma unroll
    for (int k0 = 0; k0 < DIM; k0 += 32) {
        short8 af = *(const short8*)(arow + k0);
        short8 bf = *(const short8*)(brow + k0);
        acc = __builtin_amdgcn_mfma_f32_16x16x32_bf16(af, bf, acc, 0, 0, 0);
    }
    int n = ntile * 16 + l16;
    float bb = bias[n];
#pragma unroll
    for (int r = 0; r < 4; ++r) {
        int m = mtile * 16 + quad * 4 + r;
        u16 o = f2bf(acc[r] + bb);
        if (mat == 0)      Q[(size_t)m * DIM + n] = o;
        else if (mat == 1) K[(size_t)m * DIM + n] = o;
        else               VT[(size_t)n * NTOK + m] = o;
    }
}

// ---------------- kernel 3: flash attention with bitmask ----------------
// grid (qtile=256, head=8), block 64 (one wave per head x 16 q-rows)
__global__ __launch_bounds__(64) void attn_kernel(
    const u16* __restrict__ Q, const u16* __restrict__ K, const u16* __restrict__ VT,
    const u32* __restrict__ adjbits, u16* __restrict__ AO) {
    __shared__ __align__(16) u16 plds[16 * 40];  // P tile, stride 40 bf16
    int lane = threadIdx.x, quad = lane >> 4, l16 = lane & 15;
    int qtile = blockIdx.x, h = blockIdx.y;
    int qbase = qtile * 16;
    // scale = 1/sqrt(32) * log2(e): softmax computed in base-2 domain
    const float scale2 = 0.17677669529663689f * 1.4426950408889634f;

    short8 qf = *(const short8*)(Q + (size_t)(qbase + l16) * DIM + h * HD + quad * 8);
    float m[4], l[4];
    float4v o0 = {0.f, 0.f, 0.f, 0.f}, o1 = {0.f, 0.f, 0.f, 0.f};
    const float4v zf = {0.f, 0.f, 0.f, 0.f};
#pragma unroll
    for (int r = 0; r < 4; ++r) { m[r] = -1e30f; l[r] = 0.f; }

#pragma unroll 2
    for (int k0 = 0; k0 < NTOK; k0 += 32) {
        short8 kf0 = *(const short8*)(K + (size_t)(k0 + l16) * DIM + h * HD + quad * 8);
        short8 kf1 = *(const short8*)(K + (size_t)(k0 + 16 + l16) * DIM + h * HD + quad * 8);
        short8 vf0 = *(const short8*)(VT + (size_t)(h * HD + l16) * NTOK + k0 + quad * 8);
        short8 vf1 = *(const short8*)(VT + (size_t)(h * HD + 16 + l16) * NTOK + k0 + quad * 8);
        float4v s0 = __builtin_amdgcn_mfma_f32_16x16x32_bf16(qf, kf0, zf, 0, 0, 0);
        float4v s1 = __builtin_amdgcn_mfma_f32_16x16x32_bf16(qf, kf1, zf, 0, 0, 0);
        int w32 = k0 >> 5;
        float p0[4], p1[4];
#pragma unroll
        for (int r = 0; r < 4; ++r) {
            u32 bitsr = adjbits[(size_t)(qbase + quad * 4 + r) * (NTOK / 32) + w32];
            float v0 = ((bitsr >> l16) & 1u)        ? s0[r] * scale2 : -3e38f;
            float v1 = ((bitsr >> (l16 + 16)) & 1u) ? s1[r] * scale2 : -3e38f;
            float rm = fmaxf(v0, v1);
#pragma unroll
            for (int d = 1; d < 16; d <<= 1) rm = fmaxf(rm, __shfl_xor(rm, d, 64));
            float mn = fmaxf(m[r], rm);
            float alpha = exp2f(m[r] - mn);
            m[r] = mn;
            float e0 = exp2f(v0 - mn), e1 = exp2f(v1 - mn);
            float rs = e0 + e1;
#pragma unroll
            for (int d = 1; d < 16; d <<= 1) rs += __shfl_xor(rs, d, 64);
            l[r] = l[r] * alpha + rs;
            o0[r] *= alpha; o1[r] *= alpha;
            p0[r] = e0; p1[r] = e1;
        }
        // P: C-layout -> LDS -> A-layout (bf16)
#pragma unroll
        for (int r = 0; r < 4; ++r) {
            plds[(quad * 4 + r) * 40 + l16]      = f2bf(p0[r]);
            plds[(quad * 4 + r) * 40 + 16 + l16] = f2bf(p1[r]);
        }
        short8 pa = *(const short8*)(plds + l16 * 40 + quad * 8);
        o0 = __builtin_amdgcn_mfma_f32_16x16x32_bf16(pa, vf0, o0, 0, 0, 0);
        o1 = __builtin_amdgcn_mfma_f32_16x16x32_bf16(pa, vf1, o1, 0, 0, 0);
    }
#pragma unroll
    for (int r = 0; r < 4; ++r) {
        float inv = 1.0f / l[r];
        AO[(size_t)(qbase + quad * 4 + r) * DIM + h * HD + l16]      = f2bf(o0[r] * inv);
        AO[(size_t)(qbase + quad * 4 + r) * DIM + h * HD + 16 + l16] = f2bf(o1[r] * inv);
    }
}

// ---------------- kernel 4: output projection (f32 out) ----------------
__global__ __launch_bounds__(64) void out_gemm(
    const u16* __restrict__ AO, const u16* __restrict__ WTo, const float* __restrict__ bo,
    float* __restrict__ out) {
    int lane = threadIdx.x, quad = lane >> 4, l16 = lane & 15;
    int mtile = blockIdx.x, ntile = blockIdx.y;
    const u16* arow = AO + (size_t)(mtile * 16 + l16) * DIM + quad * 8;
    const u16* brow = WTo + (size_t)(ntile * 16 + l16) * DIM + quad * 8;
    float4v acc = {0.f, 0.f, 0.f, 0.f};
#pragma unroll
    for (int k0 = 0; k0 < DIM; k0 += 32) {
        short8 af = *(const short8*)(arow + k0);
        short8 bf = *(const short8*)(brow + k0);
        acc = __builtin_amdgcn_mfma_f32_16x16x32_bf16(af, bf, acc, 0, 0, 0);
    }
    int n = ntile * 16 + l16;
    float bb = bo[n];
#pragma unroll
    for (int r = 0; r < 4; ++r)
        out[(size_t)(mtile * 16 + quad * 4 + r) * DIM + n] = acc[r] + bb;
}

extern "C" void kernel_launch(void* const* d_in, const int* in_sizes, int n_in,
                              void* d_out, int out_size, void* d_ws, size_t ws_size,
                              hipStream_t stream) {
    const float* x   = (const float*)d_in[0];
    const float* adj = (const float*)d_in[1];
    const float* Wq  = (const float*)d_in[2];
    const float* bq  = (const float*)d_in[3];
    const float* Wk  = (const float*)d_in[4];
    const float* bk  = (const float*)d_in[5];
    const float* Wv  = (const float*)d_in[6];
    const float* bv  = (const float*)d_in[7];
    const float* Wo  = (const float*)d_in[8];
    const float* bo  = (const float*)d_in[9];

    char* ws = (char*)d_ws;
    const size_t MB2 = 1u << 21;
    u16* Q   = (u16*)(ws);              // 2 MB
    u16* K   = (u16*)(ws + 1 * MB2);    // 2 MB
    u16* VT  = (u16*)(ws + 2 * MB2);    // 2 MB (transposed V: [256][4096])
    u16* AO  = (u16*)(ws + 3 * MB2);    // 2 MB
    u32* AB  = (u32*)(ws + 4 * MB2);    // 2 MB adjacency bitmask
    u16* WT  = (u16*)(ws + 5 * MB2);    // 512 KB: WqT,WkT,WvT,WoT
    u16* XB  = (u16*)(ws + 5 * MB2 + (512u << 10));   // 2 MB x in bf16

    x_to_bf16<<<dim3(1024), 256, 0, stream>>>(x, XB);
    transpose_w<<<dim3(256, 4), 256, 0, stream>>>(Wq, Wk, Wv, Wo, WT);
    adj_to_bits<<<dim3(16384), 256, 0, stream>>>(adj, AB);
    qkv_gemm<<<dim3(256, 16, 3), 64, 0, stream>>>(XB, WT, bq, bk, bv, Q, K, VT);
    attn_kernel<<<dim3(256, 8), 64, 0, stream>>>(Q, K, VT, AB, AO);
    out_gemm<<<dim3(256, 16), 64, 0, stream>>>(AO, WT + 3 * 65536, bo, (float*)d_out);
}